// Round 3
// baseline (85.712 us; speedup 1.0000x reference)
//
#include <hip/hip_runtime.h>
#include <hip/hip_bf16.h>

// Problem constants (from reference setup_inputs):
//   b=8, n=1024, m=2048, x_dim=1, Y_DIM=2 -> c=3, Z_DIM=128
constexpr int B  = 8;
constexpr int N  = 1024;
constexpr int M  = 2048;
constexpr int ZD = 128;
constexpr int JPW = 4;           // j-rows per wave
constexpr int JPB = 4 * JPW;     // j-rows per block (4 waves/block)
constexpr float EPS = 1e-8f;
constexpr float LOG2E = 1.4426950408889634f;

__global__ __launch_bounds__(256, 8) void encoder_fused(
    const float* __restrict__ x,      // (B, N, 1)
    const float* __restrict__ y,      // (B, N, 2)
    const float* __restrict__ t,      // (B, M, 1)
    const float* __restrict__ sigma,  // (3,)
    const float* __restrict__ W,      // (ZD, 3) row-major
    const float* __restrict__ bfc,    // (ZD,)
    float* __restrict__ out)          // (B, M, ZD)
{
    __shared__ float sx[N];
    __shared__ float sy1[N];
    __shared__ float sy2[N];

    const int blk  = blockIdx.x;
    const int b    = blk / (M / JPB);
    const int jt   = blk % (M / JPB);
    const int tid  = threadIdx.x;
    const int wave = tid >> 6;
    const int lane = tid & 63;

    const float s0 = sigma[0], s1 = sigma[1], s2 = sigma[2];
    // q_c = -0.5 * log2(e) * exp(-2*sigma_c):  kernel_c(d) = exp2(d*d*q_c)
    const float q0 = -0.5f * LOG2E * __builtin_amdgcn_exp2f(-2.0f * s0 * LOG2E);
    const float q1 = -0.5f * LOG2E * __builtin_amdgcn_exp2f(-2.0f * s1 * LOG2E);
    const float q2 = -0.5f * LOG2E * __builtin_amdgcn_exp2f(-2.0f * s2 * LOG2E);

    const bool uniform = (s0 == s1) && (s1 == s2);
    // Fast path pre-scale: with sc = sqrt(-q0), exp2(q0*d^2) = exp2(-((sc*t)-(sc*x))^2)
    // and the negation is a free input modifier on v_exp_f32.
    const float sc = uniform ? __builtin_amdgcn_sqrtf(-q0) : 1.0f;

    // Stage x (pre-scaled on the fast path) and y (SoA) into LDS.
    for (int i = tid; i < N; i += 256) {
        sx[i] = x[b * N + i] * sc;
        float2 yv = reinterpret_cast<const float2*>(y)[b * N + i];
        sy1[i] = yv.x;
        sy2[i] = yv.y;
    }
    __syncthreads();

    const int j0 = jt * JPB + wave * JPW;      // this wave's four j-rows
    float tj[JPW];
#pragma unroll
    for (int r = 0; r < JPW; ++r) tj[r] = t[b * M + j0 + r] * sc;

    float z0[JPW] = {0.f, 0.f, 0.f, 0.f};
    float z1[JPW] = {0.f, 0.f, 0.f, 0.f};
    float z2[JPW] = {0.f, 0.f, 0.f, 0.f};

    if (uniform) {
        // One exp serves all three channels (scales identical; sigma==0 in data).
#pragma unroll
        for (int k = 0; k < N / 64; ++k) {
            const int i = k * 64 + lane;
            const float xi = sx[i], y1 = sy1[i], y2 = sy2[i];
#pragma unroll
            for (int r = 0; r < JPW; ++r) {
                const float d = tj[r] - xi;
                const float e = __builtin_amdgcn_exp2f(-(d * d));
                z0[r] += e;
                z1[r] = fmaf(y1, e, z1[r]);
                z2[r] = fmaf(y2, e, z2[r]);
            }
        }
    } else {
        // General path: per-channel scales (sx/tj unscaled since sc==1).
#pragma unroll
        for (int k = 0; k < N / 64; ++k) {
            const int i = k * 64 + lane;
            const float xi = sx[i], y1 = sy1[i], y2 = sy2[i];
#pragma unroll
            for (int r = 0; r < JPW; ++r) {
                const float d  = tj[r] - xi;
                const float d2 = d * d;
                z0[r] += __builtin_amdgcn_exp2f(d2 * q0);
                z1[r] = fmaf(y1, __builtin_amdgcn_exp2f(d2 * q1), z1[r]);
                z2[r] = fmaf(y2, __builtin_amdgcn_exp2f(d2 * q2), z2[r]);
            }
        }
    }

    // Wave-wide butterfly reductions (all lanes end with the full sums).
#pragma unroll
    for (int off = 32; off; off >>= 1) {
#pragma unroll
        for (int r = 0; r < JPW; ++r) {
            z0[r] += __shfl_xor(z0[r], off);
            z1[r] += __shfl_xor(z1[r], off);
            z2[r] += __shfl_xor(z2[r], off);
        }
    }

    // Each lane produces 2 of the 128 outputs for each of the JPW j-rows.
    const int k0 = lane * 2;
    const float w00 = W[k0 * 3 + 0], w01 = W[k0 * 3 + 1], w02 = W[k0 * 3 + 2];
    const float w10 = W[(k0 + 1) * 3 + 0], w11 = W[(k0 + 1) * 3 + 1], w12 = W[(k0 + 1) * 3 + 2];
    const float bf0 = bfc[k0], bf1 = bfc[k0 + 1];

#pragma unroll
    for (int r = 0; r < JPW; ++r) {
        const float inv = 1.0f / (z0[r] + EPS);
        const float a1 = z1[r] * inv, a2 = z2[r] * inv;
        float2 o;
        o.x = fmaf(z0[r], w00, fmaf(a1, w01, fmaf(a2, w02, bf0)));
        o.y = fmaf(z0[r], w10, fmaf(a1, w11, fmaf(a2, w12, bf1)));
        reinterpret_cast<float2*>(out)[(size_t)(b * M + j0 + r) * (ZD / 2) + lane] = o;
    }
}

extern "C" void kernel_launch(void* const* d_in, const int* in_sizes, int n_in,
                              void* d_out, int out_size, void* d_ws, size_t ws_size,
                              hipStream_t stream) {
    const float* x     = (const float*)d_in[0];
    const float* y     = (const float*)d_in[1];
    const float* t     = (const float*)d_in[2];
    const float* sigma = (const float*)d_in[3];
    const float* W     = (const float*)d_in[4];
    const float* bfc   = (const float*)d_in[5];
    float* out = (float*)d_out;

    dim3 grid(B * (M / JPB));   // 8 * 128 = 1024 blocks
    encoder_fused<<<grid, 256, 0, stream>>>(x, y, t, sigma, W, bfc, out);
}